// Round 6
// baseline (17.030 us; speedup 1.0000x reference)
//
#include <hip/hip_runtime.h>

// MovingAvgTime: out[b,j,c] = (1/k) * sum_{a=starts[j]}^{starts[j]+k-1} x[b,a,c]
// starts[j] = min( int( (j+0.5f) * float(ncols/L) ), ncols-1 ),  ncols = L-k+1
// Shapes: B=32, L=4096, C=64, fp32.
// k=16: rolling 4-tile pipeline per block. BJ=32 j per tile, NR=48 staged rows,
// double-buffered LDS (24 KB -> 4 blocks/CU at grid 1024). global_load_lds
// staging issued EVERY phase (continuous read stream); counted s_waitcnt
// vmcnt(N) never drains stores. Nontemporal stores.
//
// Per-wave VMEM queue (in-order): L0(3) L1(3) S0(2) L2(3) S1(2) L3(3) S2(2) S3(2)
//   before T0: need L0   -> vmcnt(3)
//   before T1: need L1   -> outstanding <= S0+L2        = 5 -> vmcnt(5)
//   before T2: need L2   -> outstanding <= S1+L3        = 5 -> vmcnt(5)
//   before T3: need L3   -> outstanding <= S2           = 2 -> vmcnt(2)

#define LL   4096
#define C4   16    // float4 per row (C=64)
#define BJ   32    // j per tile
#define NR   48    // rows staged per tile (max used 47)
#define JPT  2     // j per thread
#define NSTG 3     // gload_lds per thread per tile (NR*C4/256)
#define NT   4     // tiles per block
// block: 256 threads = 16 j-groups x 16 c4 ; block covers 128 j
// grid = 32 b * 32 = 1024 blocks -> 4 blocks/CU, 96 KB LDS/CU

typedef float v4 __attribute__((ext_vector_type(4)));

__global__ __launch_bounds__(256) void mavg16_kernel(const float* __restrict__ x,
                                                     const int* __restrict__ kptr,
                                                     float* __restrict__ out) {
    __shared__ v4 lds[2 * NR * C4];   // 24576 B

    const int k = *kptr;
    const int ncols = LL - k + 1;
    const float cmap = (float)((double)ncols / (double)LL);

    // XCD-aware chunked swizzle (grid=1024, divisible by 8 -> bijective).
    // Adjacent w (adjacent j-ranges) stay on the same XCD -> halo L2 hits.
    const int nwg = (int)gridDim.x;
    const int cpx = nwg >> 3;
    const int bid = (int)blockIdx.x;
    const int w = (bid & 7) * cpx + (bid >> 3);

    const int b     = w >> 5;            // 32 blocks per batch
    const int pr    = w & 31;
    const int jbase = pr * (NT * BJ);    // 128 consecutive j per block

    const int tid = (int)threadIdx.x;
    const int c4  = tid & 15;
    const int jgl = tid >> 4;

    const v4* xb = (const v4*)x + (size_t)b * (LL * C4);
    v4*       ob = (v4*)out     + (size_t)b * (LL * C4);

    if (k == 16) {
        int sb[NT];
        #pragma unroll
        for (int t = 0; t < NT; ++t)
            sb[t] = min((int)(((float)(jbase + t * BJ) + 0.5f) * cmap), ncols - 1);

        auto stage = [&](int sbase, int bufi) {
            const int base4 = sbase * C4;
            #pragma unroll
            for (int i = 0; i < NSTG; ++i) {
                const int f = i * 256 + tid;
                const int g = min(base4 + f, LL * C4 - 1);   // clamp; clamped rows never read
                __builtin_amdgcn_global_load_lds(
                    (const __attribute__((address_space(1))) unsigned int*)(xb + g),
                    (__attribute__((address_space(3))) unsigned int*)&lds[bufi * (NR * C4) + f],
                    16, 0, 0);
            }
        };

        auto compute = [&](int tilej0, int bufi, int sbase) {
            const v4* buf = lds + bufi * (NR * C4);
            const int j0 = tilej0 + jgl * JPT;
            int s0 = min((int)(((float)j0 + 0.5f) * cmap), ncols - 1);
            const int r0 = s0 - sbase;
            v4 acc = (v4){0.f, 0.f, 0.f, 0.f};
            #pragma unroll
            for (int t = 0; t < 16; ++t) acc += buf[(r0 + t) * C4 + c4];
            __builtin_nontemporal_store(acc * 0.0625f, &ob[(size_t)j0 * C4 + c4]);
            int sn = min((int)(((float)(j0 + 1) + 0.5f) * cmap), ncols - 1) - sbase;
            v4 ra = buf[(sn + 15) * C4 + c4];
            v4 rs = buf[r0 * C4 + c4];
            if (sn != r0) acc += ra - rs;
            __builtin_nontemporal_store(acc * 0.0625f, &ob[(size_t)(j0 + 1) * C4 + c4]);
        };

        // prologue: fill both buffers
        stage(sb[0], 0);
        stage(sb[1], 1);

        // T0
        asm volatile("s_waitcnt vmcnt(3)" ::: "memory");
        __builtin_amdgcn_s_barrier();
        compute(jbase + 0 * BJ, 0, sb[0]);
        asm volatile("" ::: "memory");
        __builtin_amdgcn_s_barrier();        // buf0 free
        stage(sb[2], 0);

        // T1
        asm volatile("s_waitcnt vmcnt(5)" ::: "memory");
        __builtin_amdgcn_s_barrier();
        compute(jbase + 1 * BJ, 1, sb[1]);
        asm volatile("" ::: "memory");
        __builtin_amdgcn_s_barrier();        // buf1 free
        stage(sb[3], 1);

        // T2
        asm volatile("s_waitcnt vmcnt(5)" ::: "memory");
        __builtin_amdgcn_s_barrier();
        compute(jbase + 2 * BJ, 0, sb[2]);

        // T3
        asm volatile("s_waitcnt vmcnt(2)" ::: "memory");
        __builtin_amdgcn_s_barrier();
        compute(jbase + 3 * BJ, 1, sb[3]);
    } else {
        // generic fallback (any k), direct global reads
        const float inv = 1.0f / (float)k;
        for (int t = 0; t < NT; ++t) {
            for (int u = 0; u < JPT; ++u) {
                const int j = jbase + t * BJ + jgl * JPT + u;
                int s = min((int)(((float)j + 0.5f) * cmap), ncols - 1);
                v4 acc = (v4){0.f, 0.f, 0.f, 0.f};
                for (int a = 0; a < k; ++a) acc += xb[(size_t)(s + a) * C4 + c4];
                ob[(size_t)j * C4 + c4] = acc * inv;
            }
        }
    }
}

extern "C" void kernel_launch(void* const* d_in, const int* in_sizes, int n_in,
                              void* d_out, int out_size, void* d_ws, size_t ws_size,
                              hipStream_t stream) {
    const float* x    = (const float*)d_in[0];
    const int*   kptr = (const int*)d_in[1];
    float*       out  = (float*)d_out;
    mavg16_kernel<<<dim3(1024), dim3(256), 0, stream>>>(x, kptr, out);
}

// Round 7
// 15.678 us; speedup vs baseline: 1.0863x; 1.0863x over previous
//
#include <hip/hip_runtime.h>

// MovingAvgTime: out[b,j,c] = (1/k) * sum_{a=starts[j]}^{starts[j]+k-1} x[b,a,c]
// starts[j] = min( int( (j+0.5f) * float(ncols/L) ), ncols-1 ),  ncols = L-k+1
// Shapes: B=32, L=4096, C=64, fp32.
// R7 = R5 structure (two adjacent 64-j tiles per block, double-buffered LDS,
// global_load_lds staging, counted vmcnt waits) with PLAIN stores instead of
// nontemporal: let the 32 MB output be absorbed by L2/L3 instead of forcing
// in-kernel HBM write-through.

#define LL   4096
#define C4   16    // float4 per row (C=64)
#define BJ   64    // j per tile
#define NR   80    // rows staged per tile (max used 79)
#define JPT  4     // j per thread
#define NSTG 5     // gload_lds per thread per tile (NR*C4/256)
// block: 256 threads = 16 j-groups x 16 c4 ; grid = 32 b * 32 pairs = 1024

typedef float v4 __attribute__((ext_vector_type(4)));

__global__ __launch_bounds__(256) void mavg16_kernel(const float* __restrict__ x,
                                                     const int* __restrict__ kptr,
                                                     float* __restrict__ out) {
    __shared__ v4 lds[2 * NR * C4];   // 40960 B -> 4 blocks/CU

    const int k = *kptr;
    const int ncols = LL - k + 1;
    const float cmap = (float)((double)ncols / (double)LL);

    // XCD-aware chunked swizzle (grid=1024, divisible by 8 -> bijective)
    const int nwg = (int)gridDim.x;
    const int cpx = nwg >> 3;
    const int bid = (int)blockIdx.x;
    const int w = (bid & 7) * cpx + (bid >> 3);

    const int b  = w >> 5;      // 32 tile-pairs per batch
    const int pr = w & 31;
    const int j0_T0 = pr * 128;        // tile 0: j in [j0, j0+64)
    const int j0_T1 = pr * 128 + 64;   // tile 1: adjacent (halo = L2 hit)

    const int tid = (int)threadIdx.x;
    const int c4  = tid & 15;
    const int jgl = tid >> 4;

    const v4* xb = (const v4*)x + (size_t)b * (LL * C4);
    v4*       ob = (v4*)out     + (size_t)b * (LL * C4);

    if (k == 16) {
        int sb0 = min((int)(((float)j0_T0 + 0.5f) * cmap), ncols - 1);
        int sb1 = min((int)(((float)j0_T1 + 0.5f) * cmap), ncols - 1);

        // STAGE A (tile 0) then STAGE B (tile 1): 5+5 gload_lds per thread.
        #pragma unroll
        for (int i = 0; i < NSTG; ++i) {
            const int f = i * 256 + tid;
            const int g = min(sb0 * C4 + f, LL * C4 - 1);
            __builtin_amdgcn_global_load_lds(
                (const __attribute__((address_space(1))) unsigned int*)(xb + g),
                (__attribute__((address_space(3))) unsigned int*)&lds[f],
                16, 0, 0);
        }
        #pragma unroll
        for (int i = 0; i < NSTG; ++i) {
            const int f = i * 256 + tid;
            const int g = min(sb1 * C4 + f, LL * C4 - 1);
            __builtin_amdgcn_global_load_lds(
                (const __attribute__((address_space(1))) unsigned int*)(xb + g),
                (__attribute__((address_space(3))) unsigned int*)&lds[NR * C4 + f],
                16, 0, 0);
        }

        // Own A-loads done (B's 5 may remain in flight); then all waves' A done.
        asm volatile("s_waitcnt vmcnt(5)" ::: "memory");
        __builtin_amdgcn_s_barrier();

        const float inv = 0.0625f;

        // ---- compute tile 0 from buffer A (B reads still in flight) ----
        {
            const v4* buf = lds;
            const int j0 = j0_T0 + jgl * JPT;
            int s0 = min((int)(((float)j0 + 0.5f) * cmap), ncols - 1);
            const int r0 = s0 - sb0;
            v4 acc = (v4){0.f, 0.f, 0.f, 0.f};
            #pragma unroll
            for (int t = 0; t < 16; ++t) acc += buf[(r0 + t) * C4 + c4];
            ob[(size_t)j0 * C4 + c4] = acc * inv;
            int sp = r0;
            #pragma unroll
            for (int t = 1; t < JPT; ++t) {
                int sn = min((int)(((float)(j0 + t) + 0.5f) * cmap), ncols - 1) - sb0;
                v4 ra = buf[(sn + 15) * C4 + c4];
                v4 rs = buf[sp * C4 + c4];
                if (sn != sp) acc += ra - rs;
                sp = sn;
                ob[(size_t)(j0 + t) * C4 + c4] = acc * inv;
            }
        }

        // B's 10 loads retired (own stores may remain outstanding).
        asm volatile("s_waitcnt vmcnt(4)" ::: "memory");
        __builtin_amdgcn_s_barrier();

        // ---- compute tile 1 from buffer B ----
        {
            const v4* buf = lds + NR * C4;
            const int j0 = j0_T1 + jgl * JPT;
            int s0 = min((int)(((float)j0 + 0.5f) * cmap), ncols - 1);
            const int r0 = s0 - sb1;
            v4 acc = (v4){0.f, 0.f, 0.f, 0.f};
            #pragma unroll
            for (int t = 0; t < 16; ++t) acc += buf[(r0 + t) * C4 + c4];
            ob[(size_t)j0 * C4 + c4] = acc * inv;
            int sp = r0;
            #pragma unroll
            for (int t = 1; t < JPT; ++t) {
                int sn = min((int)(((float)(j0 + t) + 0.5f) * cmap), ncols - 1) - sb1;
                v4 ra = buf[(sn + 15) * C4 + c4];
                v4 rs = buf[sp * C4 + c4];
                if (sn != sp) acc += ra - rs;
                sp = sn;
                ob[(size_t)(j0 + t) * C4 + c4] = acc * inv;
            }
        }
    } else {
        // generic fallback (any k), direct global reads, both tiles
        const float inv = 1.0f / (float)k;
        for (int tile = 0; tile < 2; ++tile) {
            const int j0b = (tile == 0) ? j0_T0 : j0_T1;
            for (int t = 0; t < JPT; ++t) {
                const int j = j0b + jgl * JPT + t;
                int s = min((int)(((float)j + 0.5f) * cmap), ncols - 1);
                v4 acc = (v4){0.f, 0.f, 0.f, 0.f};
                for (int a = 0; a < k; ++a) acc += xb[(size_t)(s + a) * C4 + c4];
                ob[(size_t)j * C4 + c4] = acc * inv;
            }
        }
    }
}

extern "C" void kernel_launch(void* const* d_in, const int* in_sizes, int n_in,
                              void* d_out, int out_size, void* d_ws, size_t ws_size,
                              hipStream_t stream) {
    const float* x    = (const float*)d_in[0];
    const int*   kptr = (const int*)d_in[1];
    float*       out  = (float*)d_out;
    mavg16_kernel<<<dim3(1024), dim3(256), 0, stream>>>(x, kptr, out);
}

// Round 8
// 14.205 us; speedup vs baseline: 1.1989x; 1.1037x over previous
//
#include <hip/hip_runtime.h>

// MovingAvgTime: out[b,j,c] = (1/k) * sum_{a=starts[j]}^{starts[j]+k-1} x[b,a,c]
// starts[j] = min( int( (j+0.5f) * float(ncols/L) ), ncols-1 ),  ncols = L-k+1
// Shapes: B=32, L=4096, C=64, fp32.
// R8: wave-autonomous streaming. 64-thread blocks; each wave owns a private
// 20 KB LDS buffer (80 rows) covering 64 j. Stage via 20 global_load_lds,
// ONE s_waitcnt vmcnt(0) (own loads), NO s_barrier anywhere. Waves self-pace
// so device-wide read and write streams interleave. NT stores (R7 A/B win).

#define LL   4096
#define C4   16    // float4 per row (C=64)
#define BJ   64    // j per wave
#define NR   80    // rows staged (max used 79)
#define NSTG 20    // gload_lds issues per lane (NR*C4/64)
#define JPT  16    // j per lane
// block: 64 threads (1 wave) = 16 c4 x 4 j-groups; grid = 32 b * 64 = 2048
// LDS 20 KB/block -> 8 blocks/CU (160 KB), 8 waves/CU.

typedef float v4 __attribute__((ext_vector_type(4)));

__global__ __launch_bounds__(64) void mavg16_kernel(const float* __restrict__ x,
                                                    const int* __restrict__ kptr,
                                                    float* __restrict__ out) {
    __shared__ v4 lds[NR * C4];   // 20480 B, wave-private

    const int k = *kptr;
    const int ncols = LL - k + 1;
    const float cmap = (float)((double)ncols / (double)LL);

    // XCD-aware chunked swizzle (grid=2048, divisible by 8 -> bijective);
    // adjacent tiles stay on one XCD -> halo rows are L2 hits.
    const int nwg = (int)gridDim.x;
    const int cpx = nwg >> 3;
    const int bid = (int)blockIdx.x;
    const int w = (bid & 7) * cpx + (bid >> 3);

    const int b     = w >> 6;       // 64 tiles per batch
    const int tile  = w & 63;
    const int jbase = tile * BJ;

    const int tid = (int)threadIdx.x;   // 0..63
    const int c4  = tid & 15;
    const int jgl = tid >> 4;           // 0..3
    const int j0  = jbase + jgl * JPT;

    const v4* xb = (const v4*)x + (size_t)b * (LL * C4);
    v4*       ob = (v4*)out     + (size_t)b * (LL * C4);

    if (k == 16) {
        int sbase = min((int)(((float)jbase + 0.5f) * cmap), ncols - 1);
        const int base4 = sbase * C4;

        // Stage 80 rows: 20 wave-issues, lane-linear LDS dest, per-lane src.
        #pragma unroll
        for (int i = 0; i < NSTG; ++i) {
            const int f = i * 64 + tid;
            const int g = min(base4 + f, LL * C4 - 1);  // clamp; clamped rows unused
            __builtin_amdgcn_global_load_lds(
                (const __attribute__((address_space(1))) unsigned int*)(xb + g),
                (__attribute__((address_space(3))) unsigned int*)&lds[f],
                16, 0, 0);
        }
        // Wave-synchronous: wait own loads only. No s_barrier in this kernel.
        asm volatile("s_waitcnt vmcnt(0)" ::: "memory");

        const float inv = 0.0625f;
        int s0 = min((int)(((float)j0 + 0.5f) * cmap), ncols - 1);
        const int r0 = s0 - sbase;

        v4 acc = (v4){0.f, 0.f, 0.f, 0.f};
        #pragma unroll
        for (int t = 0; t < 16; ++t) acc += lds[(r0 + t) * C4 + c4];
        __builtin_nontemporal_store(acc * inv, &ob[(size_t)j0 * C4 + c4]);

        int sp = r0;
        #pragma unroll
        for (int t = 1; t < JPT; ++t) {
            int sn = min((int)(((float)(j0 + t) + 0.5f) * cmap), ncols - 1) - sbase;
            v4 ra = lds[(sn + 15) * C4 + c4];   // row entering the window
            v4 rs = lds[sp * C4 + c4];          // row leaving the window
            if (sn != sp) acc += ra - rs;
            sp = sn;
            __builtin_nontemporal_store(acc * inv, &ob[(size_t)(j0 + t) * C4 + c4]);
        }
    } else {
        // generic fallback (any k), direct global reads
        const float inv = 1.0f / (float)k;
        for (int t = 0; t < JPT; ++t) {
            const int j = j0 + t;
            int s = min((int)(((float)j + 0.5f) * cmap), ncols - 1);
            v4 acc = (v4){0.f, 0.f, 0.f, 0.f};
            for (int a = 0; a < k; ++a) acc += xb[(size_t)(s + a) * C4 + c4];
            ob[(size_t)j * C4 + c4] = acc * inv;
        }
    }
}

extern "C" void kernel_launch(void* const* d_in, const int* in_sizes, int n_in,
                              void* d_out, int out_size, void* d_ws, size_t ws_size,
                              hipStream_t stream) {
    const float* x    = (const float*)d_in[0];
    const int*   kptr = (const int*)d_in[1];
    float*       out  = (float*)d_out;
    mavg16_kernel<<<dim3(2048), dim3(64), 0, stream>>>(x, kptr, out);
}

// Round 9
// 13.808 us; speedup vs baseline: 1.2333x; 1.0288x over previous
//
#include <hip/hip_runtime.h>

// MovingAvgTime: out[b,j,c] = (1/k) * sum_{a=starts[j]}^{starts[j]+k-1} x[b,a,c]
// starts[j] = min( int( (j+0.5f) * float(ncols/L) ), ncols-1 ),  ncols = L-k+1
// Shapes: B=32, L=4096, C=64, fp32.
// R9 = revert to R5 (best: 13.81 us): two adjacent 64-j tiles per block,
// double-buffered LDS (40 KB, 4 blocks/CU), global_load_lds staging issued
// up front, counted s_waitcnt vmcnt(N) (never drains stores), raw s_barrier,
// nontemporal stores.

#define LL   4096
#define C4   16    // float4 per row (C=64)
#define BJ   64    // j per tile
#define NR   80    // rows staged per tile (max used 79)
#define JPT  4     // j per thread
#define NSTG 5     // gload_lds per thread per tile (NR*C4/256)
// block: 256 threads = 16 j-groups x 16 c4 ; grid = 32 b * 32 pairs = 1024

typedef float v4 __attribute__((ext_vector_type(4)));

__global__ __launch_bounds__(256) void mavg16_kernel(const float* __restrict__ x,
                                                     const int* __restrict__ kptr,
                                                     float* __restrict__ out) {
    __shared__ v4 lds[2 * NR * C4];   // 40960 B -> 4 blocks/CU

    const int k = *kptr;
    const int ncols = LL - k + 1;
    const float cmap = (float)((double)ncols / (double)LL);

    // XCD-aware chunked swizzle (grid=1024, divisible by 8 -> bijective)
    const int nwg = (int)gridDim.x;
    const int cpx = nwg >> 3;
    const int bid = (int)blockIdx.x;
    const int w = (bid & 7) * cpx + (bid >> 3);

    const int b  = w >> 5;      // 32 tile-pairs per batch
    const int pr = w & 31;
    const int j0_T0 = pr * 128;        // tile 0: j in [j0, j0+64)
    const int j0_T1 = pr * 128 + 64;   // tile 1: adjacent (halo = L2 hit)

    const int tid = (int)threadIdx.x;
    const int c4  = tid & 15;
    const int jgl = tid >> 4;

    const v4* xb = (const v4*)x + (size_t)b * (LL * C4);
    v4*       ob = (v4*)out     + (size_t)b * (LL * C4);

    if (k == 16) {
        int sb0 = min((int)(((float)j0_T0 + 0.5f) * cmap), ncols - 1);
        int sb1 = min((int)(((float)j0_T1 + 0.5f) * cmap), ncols - 1);

        // STAGE A (tile 0) then STAGE B (tile 1): 5+5 gload_lds per thread.
        #pragma unroll
        for (int i = 0; i < NSTG; ++i) {
            const int f = i * 256 + tid;
            const int g = min(sb0 * C4 + f, LL * C4 - 1);
            __builtin_amdgcn_global_load_lds(
                (const __attribute__((address_space(1))) unsigned int*)(xb + g),
                (__attribute__((address_space(3))) unsigned int*)&lds[f],
                16, 0, 0);
        }
        #pragma unroll
        for (int i = 0; i < NSTG; ++i) {
            const int f = i * 256 + tid;
            const int g = min(sb1 * C4 + f, LL * C4 - 1);
            __builtin_amdgcn_global_load_lds(
                (const __attribute__((address_space(1))) unsigned int*)(xb + g),
                (__attribute__((address_space(3))) unsigned int*)&lds[NR * C4 + f],
                16, 0, 0);
        }

        // Own A-loads done (B's 5 may remain in flight); then all waves' A done.
        asm volatile("s_waitcnt vmcnt(5)" ::: "memory");
        __builtin_amdgcn_s_barrier();

        const float inv = 0.0625f;

        // ---- compute tile 0 from buffer A (B reads still in flight) ----
        {
            const v4* buf = lds;
            const int j0 = j0_T0 + jgl * JPT;
            int s0 = min((int)(((float)j0 + 0.5f) * cmap), ncols - 1);
            const int r0 = s0 - sb0;
            v4 acc = (v4){0.f, 0.f, 0.f, 0.f};
            #pragma unroll
            for (int t = 0; t < 16; ++t) acc += buf[(r0 + t) * C4 + c4];
            __builtin_nontemporal_store(acc * inv, &ob[(size_t)j0 * C4 + c4]);
            int sp = r0;
            #pragma unroll
            for (int t = 1; t < JPT; ++t) {
                int sn = min((int)(((float)(j0 + t) + 0.5f) * cmap), ncols - 1) - sb0;
                v4 ra = buf[(sn + 15) * C4 + c4];
                v4 rs = buf[sp * C4 + c4];
                if (sn != sp) acc += ra - rs;
                sp = sn;
                __builtin_nontemporal_store(acc * inv, &ob[(size_t)(j0 + t) * C4 + c4]);
            }
        }

        // B's 5 loads retired (own 4 stores may remain outstanding).
        asm volatile("s_waitcnt vmcnt(4)" ::: "memory");
        __builtin_amdgcn_s_barrier();

        // ---- compute tile 1 from buffer B ----
        {
            const v4* buf = lds + NR * C4;
            const int j0 = j0_T1 + jgl * JPT;
            int s0 = min((int)(((float)j0 + 0.5f) * cmap), ncols - 1);
            const int r0 = s0 - sb1;
            v4 acc = (v4){0.f, 0.f, 0.f, 0.f};
            #pragma unroll
            for (int t = 0; t < 16; ++t) acc += buf[(r0 + t) * C4 + c4];
            __builtin_nontemporal_store(acc * inv, &ob[(size_t)j0 * C4 + c4]);
            int sp = r0;
            #pragma unroll
            for (int t = 1; t < JPT; ++t) {
                int sn = min((int)(((float)(j0 + t) + 0.5f) * cmap), ncols - 1) - sb1;
                v4 ra = buf[(sn + 15) * C4 + c4];
                v4 rs = buf[sp * C4 + c4];
                if (sn != sp) acc += ra - rs;
                sp = sn;
                __builtin_nontemporal_store(acc * inv, &ob[(size_t)(j0 + t) * C4 + c4]);
            }
        }
    } else {
        // generic fallback (any k), direct global reads, both tiles
        const float inv = 1.0f / (float)k;
        for (int tile = 0; tile < 2; ++tile) {
            const int j0b = (tile == 0) ? j0_T0 : j0_T1;
            for (int t = 0; t < JPT; ++t) {
                const int j = j0b + jgl * JPT + t;
                int s = min((int)(((float)j + 0.5f) * cmap), ncols - 1);
                v4 acc = (v4){0.f, 0.f, 0.f, 0.f};
                for (int a = 0; a < k; ++a) acc += xb[(size_t)(s + a) * C4 + c4];
                ob[(size_t)j * C4 + c4] = acc * inv;
            }
        }
    }
}

extern "C" void kernel_launch(void* const* d_in, const int* in_sizes, int n_in,
                              void* d_out, int out_size, void* d_ws, size_t ws_size,
                              hipStream_t stream) {
    const float* x    = (const float*)d_in[0];
    const int*   kptr = (const int*)d_in[1];
    float*       out  = (float*)d_out;
    mavg16_kernel<<<dim3(1024), dim3(256), 0, stream>>>(x, kptr, out);
}